// Round 1
// baseline (60314.703 us; speedup 1.0000x reference)
//
#include <hip/hip_runtime.h>
#include <stdint.h>

// Problem dims
#define Bn 64
#define Ln 256
#define En 256
#define Hn 512
#define Mn 256
#define HDn 64
#define Rn 4
#define On 1024
#define CIn 512          // E + R*HD
#define TOn 768          // H + R*HD
#define TB 1024          // threads per block (recurrent kernel)

typedef __attribute__((ext_vector_type(2))) _Float16 h2_t;

__device__ __forceinline__ float dot2(uint32_t a, uint32_t b, float c) {
  return __builtin_amdgcn_fdot2(__builtin_bit_cast(h2_t, a),
                                __builtin_bit_cast(h2_t, b), c, false);
}
__device__ __forceinline__ uint32_t pk2(float a, float b) {
  h2_t h; h.x = (_Float16)a; h.y = (_Float16)b;
  return __builtin_bit_cast(uint32_t, h);
}
__device__ __forceinline__ float sigm(float x) {
  float e = __expf(-fabsf(x)); float s = 1.0f / (1.0f + e);
  return x >= 0.0f ? s : 1.0f - s;
}
__device__ __forceinline__ float tanh_(float x) {
  float e = __expf(-2.0f * fabsf(x)); float t = (1.0f - e) / (1.0f + e);
  return x >= 0.0f ? t : -t;
}

// ---- block-wide reductions over 16 waves (all 1024 threads must call) ----
__device__ __forceinline__ void bredsum2(float& a, float& b, float* red, int tid) {
  #pragma unroll
  for (int o = 32; o; o >>= 1) { a += __shfl_xor(a, o); b += __shfl_xor(b, o); }
  __syncthreads();                       // protect red from prior use
  if ((tid & 63) == 0) { red[tid >> 6] = a; red[16 + (tid >> 6)] = b; }
  __syncthreads();
  a = 0.f; b = 0.f;
  #pragma unroll
  for (int i = 0; i < 16; i++) { a += red[i]; b += red[16 + i]; }
}
__device__ __forceinline__ float bredmax(float v, float* red, int tid) {
  #pragma unroll
  for (int o = 32; o; o >>= 1) v = fmaxf(v, __shfl_xor(v, o));
  __syncthreads();
  if ((tid & 63) == 0) red[tid >> 6] = v;
  __syncthreads();
  float r = red[0];
  #pragma unroll
  for (int i = 1; i < 16; i++) r = fmaxf(r, red[i]);
  return r;
}
__device__ __forceinline__ float bredsum(float v, float* red, int tid) {
  #pragma unroll
  for (int o = 32; o; o >>= 1) v += __shfl_xor(v, o);
  __syncthreads();
  if ((tid & 63) == 0) red[tid >> 6] = v;
  __syncthreads();
  float r = 0.f;
  #pragma unroll
  for (int i = 0; i < 16; i++) r += red[i];
  return r;
}
// LN of a 64-elem vector held one elem/lane across a full wave
__device__ __forceinline__ float ln64(float v, float g, float b) {
  float s = v;
  #pragma unroll
  for (int o = 32; o; o >>= 1) s += __shfl_xor(s, o);
  float mean = s * (1.f / 64.f);
  float d = v - mean; float q = d * d;
  #pragma unroll
  for (int o = 32; o; o >>= 1) q += __shfl_xor(q, o);
  float rstd = rsqrtf(q * (1.f / 64.f) + 1e-5f);
  return d * rstd * g + b;
}

// ---------------- weight packing kernels (run every call; one-shot cost) ----
// Gates: Wg[kk][t] : uint2 = { fp16x2 of row 2t cols (2kk,2kk+1), row 2t+1 same }
// act col c: c<512 -> ci (W_ih), c>=512 -> h (W_hh)
__global__ void pack_gates(const float* __restrict__ W_ih,
                           const float* __restrict__ W_hh,
                           uint2* __restrict__ Wg) {
  int idx = blockIdx.x * blockDim.x + threadIdx.x;   // 512*1024
  if (idx >= 512 * 1024) return;
  int t = idx >> 9, kk = idx & 511;
  int r0 = 2 * t, r1 = r0 + 1;
  float a0, a1, b0, b1;
  if (kk < 256) {
    int c = 2 * kk;
    a0 = W_ih[r0 * 512 + c]; a1 = W_ih[r0 * 512 + c + 1];
    b0 = W_ih[r1 * 512 + c]; b1 = W_ih[r1 * 512 + c + 1];
  } else {
    int c = 2 * kk - 512;
    a0 = W_hh[r0 * 512 + c]; a1 = W_hh[r0 * 512 + c + 1];
    b0 = W_hh[r1 * 512 + c]; b1 = W_hh[r1 * 512 + c + 1];
  }
  uint2 w; w.x = pk2(a0, a1); w.y = pk2(b0, b1);
  Wg[(size_t)kk * 1024 + t] = w;
}

// Heads: 512 row-slots (449 used): [0,256)=W_rk, [256,320)=W_wk, 320=W_ws,
// [321,385)=W_er, [385,449)=W_ad. Whd[kk][s] = fp16x2 of row s cols (2kk,2kk+1)
__global__ void pack_heads(const float* __restrict__ W_rk, const float* __restrict__ W_wk,
                           const float* __restrict__ W_ws, const float* __restrict__ W_er,
                           const float* __restrict__ W_ad, uint32_t* __restrict__ Whd) {
  int idx = blockIdx.x * blockDim.x + threadIdx.x;   // 512*256
  if (idx >= 512 * 256) return;
  int s = idx >> 8, kk = idx & 255;
  int c = 2 * kk;
  float a0 = 0.f, a1 = 0.f;
  if (s < 256)      { a0 = W_rk[s * 512 + c];        a1 = W_rk[s * 512 + c + 1]; }
  else if (s < 320) { a0 = W_wk[(s - 256) * 512 + c]; a1 = W_wk[(s - 256) * 512 + c + 1]; }
  else if (s == 320){ a0 = W_ws[c];                  a1 = W_ws[c + 1]; }
  else if (s < 385) { a0 = W_er[(s - 321) * 512 + c]; a1 = W_er[(s - 321) * 512 + c + 1]; }
  else if (s < 449) { a0 = W_ad[(s - 385) * 512 + c]; a1 = W_ad[(s - 385) * 512 + c + 1]; }
  Whd[(size_t)kk * 512 + s] = pk2(a0, a1);
}

// Proj: Wp[kk][o] = fp16x2 of W_proj row o cols (2kk, 2kk+1), kk<384
__global__ void pack_proj(const float* __restrict__ W_proj, uint32_t* __restrict__ Wp) {
  int idx = blockIdx.x * blockDim.x + threadIdx.x;   // 1024*384
  if (idx >= 1024 * 384) return;
  int o = idx / 384, kk = idx - o * 384;
  int c = 2 * kk;
  Wp[(size_t)kk * 1024 + o] = pk2(W_proj[o * 768 + c], W_proj[o * 768 + c + 1]);
}

// ---------------- main recurrent kernel: 1 block = 1 batch element ----------
struct Params {
  const float *x, *b_ih, *b_hh;
  const float *ln_in_g, *ln_in_b, *ln_h_g, *ln_h_b;
  const float *b_rk, *b_wk, *b_ws, *b_er, *b_ad;
  const float *ln_rk_g, *ln_rk_b, *ln_wk_g, *ln_wk_b;
  const float *ln_mem_g, *ln_mem_b, *ln_out_g, *ln_out_b;
  const uint2* Wg; const uint32_t* Whd;
  uint32_t* out16; float* out;
};

// LDS layout (floats): see carve below; total (23056 + 768)*4 = 95296 B
#define SMEM_FLOATS 23056
#define SMEM_BYTES  ((SMEM_FLOATS + 768) * 4)

__global__ __launch_bounds__(TB, 1) void dnc_recur(Params p) {
  extern __shared__ float smem[];
  float* mem  = smem;             // 16384  memory state [256][64]
  float* gbuf = mem + 16384;      // 2048   gates / reused for out-LN
  float* h32  = gbuf + 2048;      // 512
  float* c32  = h32 + 512;        // 512
  float* hn32 = c32 + 512;        // 512
  float* rv32 = hn32 + 512;       // 256
  float* cvec = rv32 + 256;       // 512
  float* hd   = cvec + 512;       // 512 (449 used) head outputs
  float* wkn  = hd + 512;         // 64   normalized write key
  float* rkn  = wkn + 64;         // 256  normalized read keys
  float* erv  = rkn + 256;        // 64
  float* wvv  = erv + 64;         // 64
  float* wsc  = wvv + 64;         // 256  write scores / ww
  float* rsc  = wsc + 256;        // 1024 read scores / rw
  float* red  = rsc + 1024;       // 64   reduction scratch
  float* misc = red + 64;         // 16   [0]=write_str
  uint32_t* act16 = (uint32_t*)(misc + 16); // 512 fp16x2: [0,256)=ci, [256,512)=h
  uint32_t* hn16  = act16 + 512;            // 256 fp16x2 of hn

  const int tid = threadIdx.x;
  const int b = blockIdx.x;

  for (int i = tid; i < Mn * HDn; i += TB) mem[i] = 0.f;
  if (tid < Hn) { h32[tid] = 0.f; c32[tid] = 0.f; }
  if (tid < 256) { rv32[tid] = 0.f; act16[256 + tid] = 0u; }
  __syncthreads();

  for (int t = 0; t < Ln; ++t) {
    // ---- Phase 0: ci = LN(concat(x_t, read_vec)), pack fp16 ----
    if (tid < 256)      cvec[tid] = p.x[((size_t)b * Ln + t) * En + tid];
    else if (tid < 512) cvec[tid] = rv32[tid - 256];
    __syncthreads();
    {
      float v = (tid < 512) ? cvec[tid] : 0.f;
      float a = v, q = v * v;
      bredsum2(a, q, red, tid);
      float mean = a * (1.f / 512.f);
      float rstd = rsqrtf(q * (1.f / 512.f) - mean * mean + 1e-5f);
      if (tid < 512)
        cvec[tid] = (cvec[tid] - mean) * rstd * p.ln_in_g[tid] + p.ln_in_b[tid];
    }
    __syncthreads();
    if (tid < 256) act16[tid] = pk2(cvec[2 * tid], cvec[2 * tid + 1]);
    __syncthreads();

    // ---- Phase 1: gates = [ci|h] @ [W_ih|W_hh]^T + biases (2 rows/thread) ----
    {
      float g0 = 0.f, g1 = 0.f;
      #pragma unroll 8
      for (int kk = 0; kk < 512; ++kk) {
        uint2 w = p.Wg[(size_t)kk * 1024 + tid];
        uint32_t a = act16[kk];
        g0 = dot2(w.x, a, g0);
        g1 = dot2(w.y, a, g1);
      }
      int r0 = 2 * tid;
      gbuf[r0]     = g0 + p.b_ih[r0]     + p.b_hh[r0];
      gbuf[r0 + 1] = g1 + p.b_ih[r0 + 1] + p.b_hh[r0 + 1];
    }
    __syncthreads();

    // ---- Phase 2: LSTM pointwise + hn = LN(h); pack hn16 + h into act16 ----
    if (tid < Hn) {
      float ig = gbuf[tid], fg = gbuf[Hn + tid], gg = gbuf[2 * Hn + tid], og = gbuf[3 * Hn + tid];
      float c = sigm(fg) * c32[tid] + sigm(ig) * tanh_(gg);
      float h = sigm(og) * tanh_(c);
      c32[tid] = c; h32[tid] = h;
    }
    __syncthreads();
    {
      float v = (tid < Hn) ? h32[tid] : 0.f;
      float a = v, q = v * v;
      bredsum2(a, q, red, tid);
      float mean = a * (1.f / Hn);
      float rstd = rsqrtf(q * (1.f / Hn) - mean * mean + 1e-5f);
      if (tid < Hn)
        hn32[tid] = (h32[tid] - mean) * rstd * p.ln_h_g[tid] + p.ln_h_b[tid];
    }
    __syncthreads();
    if (tid < 256) {
      hn16[tid] = pk2(hn32[2 * tid], hn32[2 * tid + 1]);
      act16[256 + tid] = pk2(h32[2 * tid], h32[2 * tid + 1]);  // h for next step
    }
    __syncthreads();

    // ---- Phase 3: head projections (1 row/thread, 449 rows) ----
    if (tid < 449) {
      float acc = 0.f;
      #pragma unroll 8
      for (int kk = 0; kk < 256; ++kk)
        acc = dot2(p.Whd[(size_t)kk * 512 + tid], hn16[kk], acc);
      float bias;
      if (tid < 256)      bias = p.b_rk[tid];
      else if (tid < 320) bias = p.b_wk[tid - 256];
      else if (tid == 320) bias = p.b_ws[0];
      else if (tid < 385) bias = p.b_er[tid - 321];
      else                bias = p.b_ad[tid - 385];
      hd[tid] = acc + bias;
    }
    __syncthreads();

    // ---- Phase 4: head nonlinearities + small LNs (one wave each) ----
    {
      int wid = tid >> 6, lane = tid & 63;
      if (wid == 0) {
        wkn[lane] = ln64(hd[256 + lane], p.ln_wk_g[lane], p.ln_wk_b[lane]);
      } else if (wid <= 4) {
        int n = wid - 1;
        rkn[n * 64 + lane] = ln64(hd[n * 64 + lane], p.ln_rk_g[lane], p.ln_rk_b[lane]);
      } else if (wid == 5) {
        erv[lane] = sigm(hd[321 + lane]);
      } else if (wid == 6) {
        wvv[lane] = tanh_(hd[385 + lane]);
      } else if (wid == 7 && lane == 0) {
        misc[0] = sigm(hd[320]);
      }
    }
    __syncthreads();

    // ---- Phase 5: write scores (4 threads/slot), softmax, memory update ----
    {
      int m = tid >> 2, q = tid & 3;
      const float* mrow = mem + m * HDn + q * 16;
      float s1 = 0.f, s2 = 0.f;
      #pragma unroll
      for (int j = 0; j < 16; j++) { float v = mrow[j]; s1 += v; s2 += v * v; }
      s1 += __shfl_xor(s1, 1); s1 += __shfl_xor(s1, 2);
      s2 += __shfl_xor(s2, 1); s2 += __shfl_xor(s2, 2);
      float mean = s1 * (1.f / 64.f);
      float rstd = rsqrtf(s2 * (1.f / 64.f) - mean * mean + 1e-5f);
      float d = 0.f;
      #pragma unroll
      for (int j = 0; j < 16; j++) {
        int jj = q * 16 + j;
        float mn = (mrow[j] - mean) * rstd * p.ln_mem_g[jj] + p.ln_mem_b[jj];
        d += wkn[jj] * mn;
      }
      d += __shfl_xor(d, 1); d += __shfl_xor(d, 2);
      if (q == 0) wsc[m] = d;
    }
    __syncthreads();
    {
      float v = (tid < Mn) ? wsc[tid] : -3.0e38f;
      float mx = bredmax(v, red, tid);
      float e = (tid < Mn) ? __expf(v - mx) : 0.f;
      float s = bredsum(e, red, tid);
      if (tid < Mn) wsc[tid] = e / s * misc[0];   // ww = softmax * write_str
    }
    __syncthreads();
    {
      int m = tid >> 2, q = tid & 3;
      float w = wsc[m];
      #pragma unroll
      for (int j = 0; j < 16; j++) {
        int jj = q * 16 + j;
        float v = mem[m * HDn + jj];
        mem[m * HDn + jj] = v * (1.f - w * erv[jj]) + w * wvv[jj];
      }
    }
    __syncthreads();

    // ---- Phase 7: read scores on updated memory (4 heads) ----
    {
      int m = tid >> 2, q = tid & 3;
      const float* mrow = mem + m * HDn + q * 16;
      float s1 = 0.f, s2 = 0.f;
      #pragma unroll
      for (int j = 0; j < 16; j++) { float v = mrow[j]; s1 += v; s2 += v * v; }
      s1 += __shfl_xor(s1, 1); s1 += __shfl_xor(s1, 2);
      s2 += __shfl_xor(s2, 1); s2 += __shfl_xor(s2, 2);
      float mean = s1 * (1.f / 64.f);
      float rstd = rsqrtf(s2 * (1.f / 64.f) - mean * mean + 1e-5f);
      float d0 = 0, d1 = 0, d2 = 0, d3 = 0;
      #pragma unroll
      for (int j = 0; j < 16; j++) {
        int jj = q * 16 + j;
        float mn = (mrow[j] - mean) * rstd * p.ln_mem_g[jj] + p.ln_mem_b[jj];
        d0 += rkn[jj] * mn; d1 += rkn[64 + jj] * mn;
        d2 += rkn[128 + jj] * mn; d3 += rkn[192 + jj] * mn;
      }
      d0 += __shfl_xor(d0, 1); d0 += __shfl_xor(d0, 2);
      d1 += __shfl_xor(d1, 1); d1 += __shfl_xor(d1, 2);
      d2 += __shfl_xor(d2, 1); d2 += __shfl_xor(d2, 2);
      d3 += __shfl_xor(d3, 1); d3 += __shfl_xor(d3, 2);
      if (q == 0) { rsc[m] = d0; rsc[256 + m] = d1; rsc[512 + m] = d2; rsc[768 + m] = d3; }
    }
    __syncthreads();
    // segmented softmax: head n = tid>>8 owns waves 4n..4n+3
    {
      int n = tid >> 8, m = tid & 255;
      float v = rsc[n * 256 + m];
      float mx = v;
      #pragma unroll
      for (int o = 32; o; o >>= 1) mx = fmaxf(mx, __shfl_xor(mx, o));
      if ((tid & 63) == 0) red[tid >> 6] = mx;
      __syncthreads();
      mx = fmaxf(fmaxf(red[n * 4], red[n * 4 + 1]), fmaxf(red[n * 4 + 2], red[n * 4 + 3]));
      float e = __expf(v - mx);
      float s = e;
      #pragma unroll
      for (int o = 32; o; o >>= 1) s += __shfl_xor(s, o);
      __syncthreads();
      if ((tid & 63) == 0) red[tid >> 6] = s;
      __syncthreads();
      s = red[n * 4] + red[n * 4 + 1] + red[n * 4 + 2] + red[n * 4 + 3];
      rsc[n * 256 + m] = e / s;
    }
    __syncthreads();

    // ---- Phase 8: read_vec = rw @ memory (4 threads per (n,j) output) ----
    {
      int out = tid >> 2, q = tid & 3;
      int n = out >> 6, j = out & 63;
      const float* rw = rsc + n * 256 + q * 64;
      float acc = 0.f;
      #pragma unroll 8
      for (int mm = 0; mm < 64; ++mm)
        acc += rw[mm] * mem[(q * 64 + mm) * HDn + j];
      acc += __shfl_xor(acc, 1); acc += __shfl_xor(acc, 2);
      if (q == 0) rv32[out] = acc;
    }
    __syncthreads();

    // ---- Phase 9: out = LN(concat(hn, rv)); store fp16 row for deferred proj ----
    {
      float v = 0.f;
      if (tid < Hn)       v = hn32[tid];
      else if (tid < TOn) v = rv32[tid - Hn];
      float a = v, q = v * v;
      bredsum2(a, q, red, tid);
      float mean = a * (1.f / TOn);
      float rstd = rsqrtf(q * (1.f / TOn) - mean * mean + 1e-5f);
      if (tid < TOn)
        gbuf[tid] = (v - mean) * rstd * p.ln_out_g[tid] + p.ln_out_b[tid];
    }
    __syncthreads();
    if (tid < TOn / 2)
      p.out16[((size_t)b * Ln + t) * (TOn / 2) + tid] = pk2(gbuf[2 * tid], gbuf[2 * tid + 1]);
  }

  // ---- final state outputs: memory, h, c ----
  const size_t OUT0 = (size_t)Bn * Ln * On;          // logits
  const size_t OUT1 = OUT0 + (size_t)Bn * Mn * HDn;  // memory
  const size_t OUT2 = OUT1 + (size_t)Bn * Hn;        // h
  for (int i = tid; i < Mn * HDn; i += TB)
    p.out[OUT0 + (size_t)b * Mn * HDn + i] = mem[i];
  if (tid < Hn) {
    p.out[OUT1 + (size_t)b * Hn + tid] = h32[tid];
    p.out[OUT2 + (size_t)b * Hn + tid] = c32[tid];
  }
}

// ---------------- deferred projection GEMM: [16384 x 768] @ [768 x 1024] ----
#define PROJ_ROWS 32
__global__ __launch_bounds__(1024, 1) void proj_gemm(const uint32_t* __restrict__ out16,
                                                     const uint32_t* __restrict__ Wp,
                                                     const float* __restrict__ b_proj,
                                                     float* __restrict__ out) {
  __shared__ uint32_t arow[PROJ_ROWS][384];
  int r0 = blockIdx.x * PROJ_ROWS;
  int tid = threadIdx.x;
  for (int i = tid; i < PROJ_ROWS * 384; i += 1024)
    ((uint32_t*)arow)[i] = out16[(size_t)r0 * 384 + i];
  __syncthreads();
  int cq = tid & 255, rg = tid >> 8;   // rg: 8-row group, cq + j*256: 4 cols
  float acc[8][4];
  #pragma unroll
  for (int i = 0; i < 8; i++)
    #pragma unroll
    for (int j = 0; j < 4; j++) acc[i][j] = 0.f;
  for (int kk = 0; kk < 384; ++kk) {
    uint32_t w0 = Wp[(size_t)kk * 1024 + cq];
    uint32_t w1 = Wp[(size_t)kk * 1024 + cq + 256];
    uint32_t w2 = Wp[(size_t)kk * 1024 + cq + 512];
    uint32_t w3 = Wp[(size_t)kk * 1024 + cq + 768];
    #pragma unroll
    for (int i = 0; i < 8; i++) {
      uint32_t a = arow[rg * 8 + i][kk];
      acc[i][0] = dot2(w0, a, acc[i][0]); acc[i][1] = dot2(w1, a, acc[i][1]);
      acc[i][2] = dot2(w2, a, acc[i][2]); acc[i][3] = dot2(w3, a, acc[i][3]);
    }
  }
  #pragma unroll
  for (int i = 0; i < 8; i++) {
    size_t row = (size_t)r0 + rg * 8 + i;
    #pragma unroll
    for (int j = 0; j < 4; j++) {
      int c = cq + j * 256;
      out[row * 1024 + c] = acc[i][j] + b_proj[c];
    }
  }
}

// ---------------- workspace layout (bytes) ----------------
static const size_t WS_WG    = 0;                          // uint2[512*1024]  = 4 MiB
static const size_t WS_WHD   = WS_WG  + (size_t)512 * 1024 * 8;   // uint[256*512]
static const size_t WS_WPJ   = WS_WHD + (size_t)256 * 512 * 4;    // uint[384*1024]
static const size_t WS_OUT16 = WS_WPJ + (size_t)384 * 1024 * 4;   // uint[16384*384]

extern "C" void kernel_launch(void* const* d_in, const int* in_sizes, int n_in,
                              void* d_out, int out_size, void* d_ws, size_t ws_size,
                              hipStream_t stream) {
  (void)in_sizes; (void)n_in; (void)out_size; (void)ws_size;
  const float* x       = (const float*)d_in[0];
  const float* W_ih    = (const float*)d_in[1];
  const float* W_hh    = (const float*)d_in[2];
  const float* b_ih    = (const float*)d_in[3];
  const float* b_hh    = (const float*)d_in[4];
  const float* ln_in_g = (const float*)d_in[5];
  const float* ln_in_b = (const float*)d_in[6];
  const float* ln_h_g  = (const float*)d_in[7];
  const float* ln_h_b  = (const float*)d_in[8];
  const float* W_rk    = (const float*)d_in[9];
  const float* b_rk    = (const float*)d_in[10];
  const float* W_wk    = (const float*)d_in[11];
  const float* b_wk    = (const float*)d_in[12];
  const float* W_ws    = (const float*)d_in[13];
  const float* b_ws    = (const float*)d_in[14];
  const float* W_er    = (const float*)d_in[15];
  const float* b_er    = (const float*)d_in[16];
  const float* W_ad    = (const float*)d_in[17];
  const float* b_ad    = (const float*)d_in[18];
  const float* ln_rk_g = (const float*)d_in[19];
  const float* ln_rk_b = (const float*)d_in[20];
  const float* ln_wk_g = (const float*)d_in[21];
  const float* ln_wk_b = (const float*)d_in[22];
  const float* ln_mem_g= (const float*)d_in[23];
  const float* ln_mem_b= (const float*)d_in[24];
  const float* ln_out_g= (const float*)d_in[25];
  const float* ln_out_b= (const float*)d_in[26];
  const float* W_proj  = (const float*)d_in[27];
  const float* b_proj  = (const float*)d_in[28];

  char* ws = (char*)d_ws;
  uint2*    Wg    = (uint2*)(ws + WS_WG);
  uint32_t* Whd   = (uint32_t*)(ws + WS_WHD);
  uint32_t* Wp    = (uint32_t*)(ws + WS_WPJ);
  uint32_t* out16 = (uint32_t*)(ws + WS_OUT16);

  hipLaunchKernelGGL(pack_gates, dim3(2048), dim3(256), 0, stream, W_ih, W_hh, Wg);
  hipLaunchKernelGGL(pack_heads, dim3(512), dim3(256), 0, stream,
                     W_rk, W_wk, W_ws, W_er, W_ad, Whd);
  hipLaunchKernelGGL(pack_proj, dim3(1536), dim3(256), 0, stream, W_proj, Wp);

  Params p;
  p.x = x; p.b_ih = b_ih; p.b_hh = b_hh;
  p.ln_in_g = ln_in_g; p.ln_in_b = ln_in_b; p.ln_h_g = ln_h_g; p.ln_h_b = ln_h_b;
  p.b_rk = b_rk; p.b_wk = b_wk; p.b_ws = b_ws; p.b_er = b_er; p.b_ad = b_ad;
  p.ln_rk_g = ln_rk_g; p.ln_rk_b = ln_rk_b; p.ln_wk_g = ln_wk_g; p.ln_wk_b = ln_wk_b;
  p.ln_mem_g = ln_mem_g; p.ln_mem_b = ln_mem_b; p.ln_out_g = ln_out_g; p.ln_out_b = ln_out_b;
  p.Wg = Wg; p.Whd = Whd; p.out16 = out16; p.out = (float*)d_out;

  hipLaunchKernelGGL(dnc_recur, dim3(Bn), dim3(TB), SMEM_BYTES, stream, p);
  hipLaunchKernelGGL(proj_gemm, dim3((Bn * Ln) / PROJ_ROWS), dim3(1024), 0, stream,
                     out16, Wp, b_proj, (float*)d_out);
}

// Round 2
// 18570.647 us; speedup vs baseline: 3.2479x; 3.2479x over previous
//
#include <hip/hip_runtime.h>
#include <stdint.h>

// Problem dims
#define Bn 64
#define Ln 256
#define En 256
#define Hn 512
#define Mn 256
#define HDn 64
#define Rn 4
#define On 1024
#define CIn 512          // E + R*HD
#define TOn 768          // H + R*HD
#define TB 1024          // threads per block (recurrent kernel)
#define MP 65            // padded row stride of memory in LDS (bank-conflict fix)

typedef __attribute__((ext_vector_type(2))) _Float16 h2_t;

__device__ __forceinline__ float dot2(uint32_t a, uint32_t b, float c) {
  return __builtin_amdgcn_fdot2(__builtin_bit_cast(h2_t, a),
                                __builtin_bit_cast(h2_t, b), c, false);
}
__device__ __forceinline__ uint32_t pk2(float a, float b) {
  h2_t h; h.x = (_Float16)a; h.y = (_Float16)b;
  return __builtin_bit_cast(uint32_t, h);
}
__device__ __forceinline__ float sigm(float x) {
  float e = __expf(-fabsf(x)); float s = 1.0f / (1.0f + e);
  return x >= 0.0f ? s : 1.0f - s;
}
__device__ __forceinline__ float tanh_(float x) {
  float e = __expf(-2.0f * fabsf(x)); float t = (1.0f - e) / (1.0f + e);
  return x >= 0.0f ? t : -t;
}
// LN of a 64-elem vector held one elem/lane across a full wave
__device__ __forceinline__ float ln64(float v, float g, float b) {
  float s = v;
  #pragma unroll
  for (int o = 32; o; o >>= 1) s += __shfl_xor(s, o);
  float mean = s * (1.f / 64.f);
  float d = v - mean; float q = d * d;
  #pragma unroll
  for (int o = 32; o; o >>= 1) q += __shfl_xor(q, o);
  float rstd = rsqrtf(q * (1.f / 64.f) + 1e-5f);
  return d * rstd * g + b;
}

// ---------------- weight packing kernels ----------------
// Gates: Wg4[kk][u] : uint4 = fp16x2 (cols 2kk,2kk+1) of rows {u, 512+u, 1024+u, 1536+u}
// i.e. the i,f,g,o gate rows of hidden unit u. col<512 -> W_ih, col>=512 -> W_hh.
__global__ void pack_gates4(const float* __restrict__ W_ih,
                            const float* __restrict__ W_hh,
                            uint4* __restrict__ Wg4) {
  int idx = blockIdx.x * 256 + threadIdx.x;   // 512*512
  if (idx >= 512 * 512) return;
  int kk = idx >> 9, u = idx & 511;
  int c = 2 * kk;
  float v[8];
  #pragma unroll
  for (int r = 0; r < 4; r++) {
    int row = r * 512 + u;
    float a, bb;
    if (c < 512) { a = W_ih[row * 512 + c];        bb = W_ih[row * 512 + c + 1]; }
    else         { a = W_hh[row * 512 + (c - 512)]; bb = W_hh[row * 512 + (c - 512) + 1]; }
    v[2 * r] = a; v[2 * r + 1] = bb;
  }
  uint4 w; w.x = pk2(v[0], v[1]); w.y = pk2(v[2], v[3]);
  w.z = pk2(v[4], v[5]); w.w = pk2(v[6], v[7]);
  Wg4[(size_t)kk * 512 + u] = w;
}

// Heads: 512 padded row slots: [0,256)=W_rk, [256,320)=W_wk, 320=W_ws,
// [321,385)=W_er, [385,449)=W_ad, rest 0. Whd4[kk][s4] = rows 4s4..4s4+3.
__global__ void pack_heads4(const float* __restrict__ W_rk, const float* __restrict__ W_wk,
                            const float* __restrict__ W_ws, const float* __restrict__ W_er,
                            const float* __restrict__ W_ad, uint4* __restrict__ Whd4) {
  int idx = blockIdx.x * 256 + threadIdx.x;   // 256*128
  if (idx >= 256 * 128) return;
  int kk = idx >> 7, s4 = idx & 127;
  int c = 2 * kk;
  float v[8];
  #pragma unroll
  for (int j = 0; j < 4; j++) {
    int s = 4 * s4 + j;
    float a = 0.f, bb = 0.f;
    if (s < 256)      { a = W_rk[s * 512 + c];          bb = W_rk[s * 512 + c + 1]; }
    else if (s < 320) { a = W_wk[(s - 256) * 512 + c];  bb = W_wk[(s - 256) * 512 + c + 1]; }
    else if (s == 320){ a = W_ws[c];                    bb = W_ws[c + 1]; }
    else if (s < 385) { a = W_er[(s - 321) * 512 + c];  bb = W_er[(s - 321) * 512 + c + 1]; }
    else if (s < 449) { a = W_ad[(s - 385) * 512 + c];  bb = W_ad[(s - 385) * 512 + c + 1]; }
    v[2 * j] = a; v[2 * j + 1] = bb;
  }
  uint4 w; w.x = pk2(v[0], v[1]); w.y = pk2(v[2], v[3]);
  w.z = pk2(v[4], v[5]); w.w = pk2(v[6], v[7]);
  Whd4[(size_t)kk * 128 + s4] = w;
}

// Proj: Wp[kk][o] = fp16x2 of W_proj row o cols (2kk, 2kk+1), kk<384
__global__ void pack_proj(const float* __restrict__ W_proj, uint32_t* __restrict__ Wp) {
  int idx = blockIdx.x * blockDim.x + threadIdx.x;   // 1024*384
  if (idx >= 1024 * 384) return;
  int o = idx / 384, kk = idx - o * 384;
  int c = 2 * kk;
  Wp[(size_t)kk * 1024 + o] = pk2(W_proj[o * 768 + c], W_proj[o * 768 + c + 1]);
}

// ---------------- main recurrent kernel: 1 block = 1 batch element ----------
struct Params {
  const float *x, *b_ih, *b_hh;
  const float *ln_in_g, *ln_in_b, *ln_h_g, *ln_h_b;
  const float *b_rk, *b_wk, *b_ws, *b_er, *b_ad;
  const float *ln_rk_g, *ln_rk_b, *ln_wk_g, *ln_wk_b;
  const float *ln_mem_g, *ln_mem_b, *ln_out_g, *ln_out_b;
  const uint4* Wg4; const uint4* Whd4;
  uint32_t* out16; float* out;
};

#define SMEM_FLOATS 32736
#define SMEM_BYTES  (SMEM_FLOATS * 4)

__global__ __launch_bounds__(TB, 1) void dnc_recur(Params p) {
  extern __shared__ float smem[];
  float* mem  = smem;             // 256*65 = 16640 memory state (padded stride)
  float* h32  = mem + 16640;      // 512
  float* c32  = h32 + 512;        // 512
  float* hn32 = c32 + 512;        // 512
  float* rv32 = hn32 + 512;       // 256
  float* cvec = rv32 + 256;       // 512
  float* hd   = cvec + 512;       // 512 head outputs
  float* wkn  = hd + 512;         // 64
  float* rkn  = wkn + 64;         // 256
  float* erv  = rkn + 256;        // 64
  float* wvv  = erv + 64;         // 64
  float* wsc  = wvv + 64;         // 256
  float* rsc  = wsc + 256;        // 1024
  float* redA = rsc + 1024;       // 32
  float* redB = redA + 32;        // 32
  float* redC = redB + 32;        // 16
  float* redD = redC + 16;        // 32
  float* redE = redD + 32;        // 32
  float* misc = redE + 32;        // 16  [0]=write_str
  float* gpart= misc + 16;        // 4096 gate partials (2x2048) / head partials (8x512)
  float* Lin_g= gpart + 4096;     // 512
  float* Lin_b= Lin_g + 512;      // 512
  float* Lh_g = Lin_b + 512;      // 512
  float* Lh_b = Lh_g + 512;       // 512
  float* Lo_g = Lh_b + 512;       // 768
  float* Lo_b = Lo_g + 768;       // 768
  float* Lrk_g= Lo_b + 768;       // 64
  float* Lrk_b= Lrk_g + 64;       // 64
  float* Lwk_g= Lrk_b + 64;       // 64
  float* Lwk_b= Lwk_g + 64;       // 64
  float* Lm_g = Lwk_b + 64;       // 64
  float* Lm_b = Lm_g + 64;        // 64
  float* bsum = Lm_b + 64;        // 2048 (float4[512]: combined i,f,g,o biases)
  float* bhd  = bsum + 2048;      // 512  head biases in slot order
  uint32_t* act16 = (uint32_t*)(bhd + 512); // 512: [0,256)=ci fp16x2, [256,512)=h fp16x2
  uint32_t* hn16  = act16 + 512;            // 256: hn fp16x2

  const int tid = threadIdx.x;
  const int b = blockIdx.x;

  // ---- one-time staging: params to LDS, zero state ----
  for (int i = tid; i < 16640; i += TB) mem[i] = 0.f;
  if (tid < 512) {
    h32[tid] = 0.f; c32[tid] = 0.f;
    Lin_g[tid] = p.ln_in_g[tid]; Lin_b[tid] = p.ln_in_b[tid];
    Lh_g[tid]  = p.ln_h_g[tid];  Lh_b[tid]  = p.ln_h_b[tid];
    float4 bs;
    bs.x = p.b_ih[tid]        + p.b_hh[tid];
    bs.y = p.b_ih[512 + tid]  + p.b_hh[512 + tid];
    bs.z = p.b_ih[1024 + tid] + p.b_hh[1024 + tid];
    bs.w = p.b_ih[1536 + tid] + p.b_hh[1536 + tid];
    ((float4*)bsum)[tid] = bs;
    float bb = 0.f;
    if (tid < 256)       bb = p.b_rk[tid];
    else if (tid < 320)  bb = p.b_wk[tid - 256];
    else if (tid == 320) bb = p.b_ws[0];
    else if (tid < 385)  bb = p.b_er[tid - 321];
    else if (tid < 449)  bb = p.b_ad[tid - 385];
    bhd[tid] = bb;
  }
  if (tid < 768) { Lo_g[tid] = p.ln_out_g[tid]; Lo_b[tid] = p.ln_out_b[tid]; }
  if (tid < 64) {
    Lrk_g[tid] = p.ln_rk_g[tid]; Lrk_b[tid] = p.ln_rk_b[tid];
    Lwk_g[tid] = p.ln_wk_g[tid]; Lwk_b[tid] = p.ln_wk_b[tid];
    Lm_g[tid]  = p.ln_mem_g[tid]; Lm_b[tid] = p.ln_mem_b[tid];
  }
  if (tid < 256) { rv32[tid] = 0.f; act16[256 + tid] = 0u; }
  __syncthreads();

  for (int t = 0; t < Ln; ++t) {
    // ---- P0: stage ci = concat(x_t, read_vec) ----
    if (tid < 256)      cvec[tid] = p.x[((size_t)b * Ln + t) * En + tid];
    else if (tid < 512) cvec[tid] = rv32[tid - 256];
    __syncthreads();                                                 // A
    {  // LN(ci) partials
      float v = (tid < 512) ? cvec[tid] : 0.f;
      float s = v, q = v * v;
      #pragma unroll
      for (int o = 32; o; o >>= 1) { s += __shfl_xor(s, o); q += __shfl_xor(q, o); }
      if ((tid & 63) == 0) { redA[tid >> 6] = s; redA[16 + (tid >> 6)] = q; }
    }
    __syncthreads();                                                 // B
    {
      float s = 0.f, q = 0.f;
      #pragma unroll
      for (int i = 0; i < 16; i++) { s += redA[i]; q += redA[16 + i]; }
      float mean = s * (1.f / 512.f);
      float rstd = rsqrtf(q * (1.f / 512.f) - mean * mean + 1e-5f);
      if (tid < 256) {
        float v0 = (cvec[2 * tid]     - mean) * rstd * Lin_g[2 * tid]     + Lin_b[2 * tid];
        float v1 = (cvec[2 * tid + 1] - mean) * rstd * Lin_g[2 * tid + 1] + Lin_b[2 * tid + 1];
        act16[tid] = pk2(v0, v1);
      }
    }
    __syncthreads();                                                 // C

    // ---- P1: gates. thread = (k-half, unit). 4 rows (i,f,g,o of unit), 256 kk.
    {
      int u = tid & 511, kh = tid >> 9;
      const uint4* wp = p.Wg4 + (size_t)(kh * 256) * 512 + u;
      const uint32_t* ap = act16 + kh * 256;
      float a0 = 0.f, a1 = 0.f, a2 = 0.f, a3 = 0.f;
      uint4 Ab[8], Bb[8];
      #pragma unroll
      for (int j = 0; j < 8; j++) Ab[j] = wp[(size_t)j * 512];
      #pragma unroll 1
      for (int c = 0; c < 32; c += 2) {
        #pragma unroll
        for (int j = 0; j < 8; j++) Bb[j] = wp[(size_t)((c + 1) * 8 + j) * 512];
        #pragma unroll
        for (int j = 0; j < 8; j++) {
          uint32_t a = ap[c * 8 + j];
          a0 = dot2(Ab[j].x, a, a0); a1 = dot2(Ab[j].y, a, a1);
          a2 = dot2(Ab[j].z, a, a2); a3 = dot2(Ab[j].w, a, a3);
        }
        int cn = (c + 2) & 31;   // c=30 -> dummy reload of chunk 0 (branch-free)
        #pragma unroll
        for (int j = 0; j < 8; j++) Ab[j] = wp[(size_t)(cn * 8 + j) * 512];
        #pragma unroll
        for (int j = 0; j < 8; j++) {
          uint32_t a = ap[(c + 1) * 8 + j];
          a0 = dot2(Bb[j].x, a, a0); a1 = dot2(Bb[j].y, a, a1);
          a2 = dot2(Bb[j].z, a, a2); a3 = dot2(Bb[j].w, a, a3);
        }
      }
      float4 r; r.x = a0; r.y = a1; r.z = a2; r.w = a3;
      ((float4*)(gpart + kh * 2048))[u] = r;
    }
    __syncthreads();                                                 // D

    // ---- P2: combine k-halves + LSTM pointwise ----
    if (tid < 512) {
      float4 pa = ((float4*)gpart)[tid];
      float4 pb = ((float4*)gpart)[512 + tid];
      float4 bs = ((float4*)bsum)[tid];
      float gi = pa.x + pb.x + bs.x;
      float gf = pa.y + pb.y + bs.y;
      float gg = pa.z + pb.z + bs.z;
      float go = pa.w + pb.w + bs.w;
      float c_ = sigm(gf) * c32[tid] + sigm(gi) * tanh_(gg);
      float h_ = sigm(go) * tanh_(c_);
      c32[tid] = c_; h32[tid] = h_;
    }
    __syncthreads();                                                 // E
    {  // LN(h) partials
      float v = (tid < 512) ? h32[tid] : 0.f;
      float s = v, q = v * v;
      #pragma unroll
      for (int o = 32; o; o >>= 1) { s += __shfl_xor(s, o); q += __shfl_xor(q, o); }
      if ((tid & 63) == 0) { redB[tid >> 6] = s; redB[16 + (tid >> 6)] = q; }
    }
    __syncthreads();                                                 // F
    {
      float s = 0.f, q = 0.f;
      #pragma unroll
      for (int i = 0; i < 16; i++) { s += redB[i]; q += redB[16 + i]; }
      float mean = s * (1.f / Hn);
      float rstd = rsqrtf(q * (1.f / Hn) - mean * mean + 1e-5f);
      if (tid < 512) hn32[tid] = (h32[tid] - mean) * rstd * Lh_g[tid] + Lh_b[tid];
      if (tid < 256) {
        float v0 = (h32[2 * tid]     - mean) * rstd * Lh_g[2 * tid]     + Lh_b[2 * tid];
        float v1 = (h32[2 * tid + 1] - mean) * rstd * Lh_g[2 * tid + 1] + Lh_b[2 * tid + 1];
        hn16[tid] = pk2(v0, v1);
        act16[256 + tid] = pk2(h32[2 * tid], h32[2 * tid + 1]);   // h for next step
      }
    }
    __syncthreads();                                                 // G

    // ---- P3: heads. thread = (k-part 0..7, row-group 0..127). 32 kk each.
    {
      int s4 = tid & 127, kp = tid >> 7;
      const uint4* wp = p.Whd4 + (size_t)(kp * 32) * 128 + s4;
      const uint32_t* ap = hn16 + kp * 32;
      float a0 = 0.f, a1 = 0.f, a2 = 0.f, a3 = 0.f;
      uint4 Ab[8], Bb[8];
      #pragma unroll
      for (int j = 0; j < 8; j++) Ab[j] = wp[(size_t)j * 128];
      #pragma unroll 1
      for (int c = 0; c < 4; c += 2) {
        #pragma unroll
        for (int j = 0; j < 8; j++) Bb[j] = wp[(size_t)((c + 1) * 8 + j) * 128];
        #pragma unroll
        for (int j = 0; j < 8; j++) {
          uint32_t a = ap[c * 8 + j];
          a0 = dot2(Ab[j].x, a, a0); a1 = dot2(Ab[j].y, a, a1);
          a2 = dot2(Ab[j].z, a, a2); a3 = dot2(Ab[j].w, a, a3);
        }
        int cn = (c + 2) & 3;
        #pragma unroll
        for (int j = 0; j < 8; j++) Ab[j] = wp[(size_t)(cn * 8 + j) * 128];
        #pragma unroll
        for (int j = 0; j < 8; j++) {
          uint32_t a = ap[(c + 1) * 8 + j];
          a0 = dot2(Bb[j].x, a, a0); a1 = dot2(Bb[j].y, a, a1);
          a2 = dot2(Bb[j].z, a, a2); a3 = dot2(Bb[j].w, a, a3);
        }
      }
      float4 r; r.x = a0; r.y = a1; r.z = a2; r.w = a3;
      ((float4*)(gpart + kp * 512))[s4] = r;
    }
    __syncthreads();                                                 // H
    if (tid < 512) {   // combine 8 k-parts
      float acc = bhd[tid];
      #pragma unroll
      for (int kp = 0; kp < 8; kp++) acc += gpart[kp * 512 + tid];
      hd[tid] = acc;
    }
    __syncthreads();                                                 // I

    // ---- P4: head nonlinearities + small LNs (one wave each) ----
    {
      int wid = tid >> 6, lane = tid & 63;
      if (wid == 0) {
        wkn[lane] = ln64(hd[256 + lane], Lwk_g[lane], Lwk_b[lane]);
      } else if (wid <= 4) {
        int n = wid - 1;
        rkn[n * 64 + lane] = ln64(hd[n * 64 + lane], Lrk_g[lane], Lrk_b[lane]);
      } else if (wid == 5) {
        erv[lane] = sigm(hd[321 + lane]);
      } else if (wid == 6) {
        wvv[lane] = tanh_(hd[385 + lane]);
      } else if (wid == 7 && lane == 0) {
        misc[0] = sigm(hd[320]);
      }
    }
    __syncthreads();                                                 // J

    // ---- P5: write scores (4 threads/slot, LN(mem) on the fly) ----
    {
      int m = tid >> 2, q = tid & 3;
      const float* mrow = mem + m * MP + q * 16;
      float s1 = 0.f, s2 = 0.f;
      #pragma unroll
      for (int j = 0; j < 16; j++) { float v = mrow[j]; s1 += v; s2 += v * v; }
      s1 += __shfl_xor(s1, 1); s1 += __shfl_xor(s1, 2);
      s2 += __shfl_xor(s2, 1); s2 += __shfl_xor(s2, 2);
      float mean = s1 * (1.f / 64.f);
      float rstd = rsqrtf(s2 * (1.f / 64.f) - mean * mean + 1e-5f);
      float d = 0.f;
      #pragma unroll
      for (int j = 0; j < 16; j++) {
        int jj = q * 16 + j;
        float mn = (mrow[j] - mean) * rstd * Lm_g[jj] + Lm_b[jj];
        d += wkn[jj] * mn;
      }
      d += __shfl_xor(d, 1); d += __shfl_xor(d, 2);
      if (q == 0) wsc[m] = d;
    }
    __syncthreads();                                                 // K
    // write softmax (online, tid<256 = 4 waves)
    float wsv = 0.f;
    if (tid < 256) {
      wsv = wsc[tid];
      float mx = wsv;
      #pragma unroll
      for (int o = 32; o; o >>= 1) mx = fmaxf(mx, __shfl_xor(mx, o));
      float e = __expf(wsv - mx);
      float sm = e;
      #pragma unroll
      for (int o = 32; o; o >>= 1) sm += __shfl_xor(sm, o);
      if ((tid & 63) == 0) { redC[tid >> 6] = mx; redC[8 + (tid >> 6)] = sm; }
    }
    __syncthreads();                                                 // L
    if (tid < 256) {
      float M = fmaxf(fmaxf(redC[0], redC[1]), fmaxf(redC[2], redC[3]));
      float S = redC[8]  * __expf(redC[0] - M) + redC[9]  * __expf(redC[1] - M)
              + redC[10] * __expf(redC[2] - M) + redC[11] * __expf(redC[3] - M);
      wsc[tid] = __expf(wsv - M) / S * misc[0];
    }
    __syncthreads();                                                 // M

    // ---- P6+P7 fused: memory update, then read scores on updated rows ----
    {
      int m = tid >> 2, q = tid & 3;
      float w = wsc[m];
      float* mrow = mem + m * MP + q * 16;
      float vals[16];
      float s1 = 0.f, s2 = 0.f;
      #pragma unroll
      for (int j = 0; j < 16; j++) {
        int jj = q * 16 + j;
        float v = mrow[j];
        v = v * (1.f - w * erv[jj]) + w * wvv[jj];
        mrow[j] = v;
        vals[j] = v;
        s1 += v; s2 += v * v;
      }
      s1 += __shfl_xor(s1, 1); s1 += __shfl_xor(s1, 2);
      s2 += __shfl_xor(s2, 1); s2 += __shfl_xor(s2, 2);
      float mean = s1 * (1.f / 64.f);
      float rstd = rsqrtf(s2 * (1.f / 64.f) - mean * mean + 1e-5f);
      float d0 = 0.f, d1 = 0.f, d2 = 0.f, d3 = 0.f;
      #pragma unroll
      for (int j = 0; j < 16; j++) {
        int jj = q * 16 + j;
        float mn = (vals[j] - mean) * rstd * Lm_g[jj] + Lm_b[jj];
        d0 += rkn[jj] * mn;       d1 += rkn[64 + jj] * mn;
        d2 += rkn[128 + jj] * mn; d3 += rkn[192 + jj] * mn;
      }
      d0 += __shfl_xor(d0, 1); d0 += __shfl_xor(d0, 2);
      d1 += __shfl_xor(d1, 1); d1 += __shfl_xor(d1, 2);
      d2 += __shfl_xor(d2, 1); d2 += __shfl_xor(d2, 2);
      d3 += __shfl_xor(d3, 1); d3 += __shfl_xor(d3, 2);
      if (q == 0) { rsc[m] = d0; rsc[256 + m] = d1; rsc[512 + m] = d2; rsc[768 + m] = d3; }
    }
    __syncthreads();                                                 // N
    // read softmax (online, 4 heads x 4 waves)
    float rsv;
    {
      int w = tid >> 6;
      rsv = rsc[tid];
      float mx = rsv;
      #pragma unroll
      for (int o = 32; o; o >>= 1) mx = fmaxf(mx, __shfl_xor(mx, o));
      float e = __expf(rsv - mx);
      float sm = e;
      #pragma unroll
      for (int o = 32; o; o >>= 1) sm += __shfl_xor(sm, o);
      if ((tid & 63) == 0) { redD[w] = mx; redD[16 + w] = sm; }
    }
    __syncthreads();                                                 // O
    {
      int n = tid >> 8;
      float M = fmaxf(fmaxf(redD[4 * n], redD[4 * n + 1]),
                      fmaxf(redD[4 * n + 2], redD[4 * n + 3]));
      float S = redD[16 + 4 * n]     * __expf(redD[4 * n]     - M)
              + redD[16 + 4 * n + 1] * __expf(redD[4 * n + 1] - M)
              + redD[16 + 4 * n + 2] * __expf(redD[4 * n + 2] - M)
              + redD[16 + 4 * n + 3] * __expf(redD[4 * n + 3] - M);
      rsc[tid] = __expf(rsv - M) / S;
    }
    __syncthreads();                                                 // P

    // ---- P8: read_vec = rw @ memory (4 threads per output, mm-quarters) ----
    {
      int out = tid >> 2, q = tid & 3;
      int n = out >> 6, j = out & 63;
      const float* rw = rsc + n * 256 + q * 64;
      float acc = 0.f;
      #pragma unroll 8
      for (int mm = 0; mm < 64; ++mm)
        acc += rw[mm] * mem[(q * 64 + mm) * MP + j];
      acc += __shfl_xor(acc, 1); acc += __shfl_xor(acc, 2);
      if (q == 0) rv32[out] = acc;
    }
    __syncthreads();                                                 // Q

    // ---- P9: out = LN(concat(hn, rv)) -> fp16 row for deferred proj ----
    {
      float v = (tid < 512) ? hn32[tid] : (tid < 768 ? rv32[tid - 512] : 0.f);
      float s = v, q = v * v;
      #pragma unroll
      for (int o = 32; o; o >>= 1) { s += __shfl_xor(s, o); q += __shfl_xor(q, o); }
      if ((tid & 63) == 0) { redE[tid >> 6] = s; redE[16 + (tid >> 6)] = q; }
    }
    __syncthreads();                                                 // R
    {
      float s = 0.f, q = 0.f;
      #pragma unroll
      for (int i = 0; i < 16; i++) { s += redE[i]; q += redE[16 + i]; }
      float mean = s * (1.f / TOn);
      float rstd = rsqrtf(q * (1.f / TOn) - mean * mean + 1e-5f);
      if (tid < 384) {
        int e0 = 2 * tid, e1 = e0 + 1;
        float u0 = (e0 < 512) ? hn32[e0] : rv32[e0 - 512];
        float u1 = (e1 < 512) ? hn32[e1] : rv32[e1 - 512];
        u0 = (u0 - mean) * rstd * Lo_g[e0] + Lo_b[e0];
        u1 = (u1 - mean) * rstd * Lo_g[e1] + Lo_b[e1];
        p.out16[((size_t)b * Ln + t) * 384 + tid] = pk2(u0, u1);
      }
    }
    // no trailing barrier needed: next-iter writes don't alias this phase's reads
  }

  // ---- final state outputs: memory, h, c ----
  const size_t OUT0 = (size_t)Bn * Ln * On;
  const size_t OUT1 = OUT0 + (size_t)Bn * Mn * HDn;
  const size_t OUT2 = OUT1 + (size_t)Bn * Hn;
  for (int i = tid; i < Mn * HDn; i += TB)
    p.out[OUT0 + (size_t)b * Mn * HDn + i] = mem[(i >> 6) * MP + (i & 63)];
  if (tid < Hn) {
    p.out[OUT1 + (size_t)b * Hn + tid] = h32[tid];
    p.out[OUT2 + (size_t)b * Hn + tid] = c32[tid];
  }
}

// ---------------- deferred projection GEMM: [16384 x 768] @ [768 x 1024] ----
#define PROJ_ROWS 32
__global__ __launch_bounds__(1024, 1) void proj_gemm(const uint32_t* __restrict__ out16,
                                                     const uint32_t* __restrict__ Wp,
                                                     const float* __restrict__ b_proj,
                                                     float* __restrict__ out) {
  __shared__ uint32_t arow[PROJ_ROWS][384];
  int r0 = blockIdx.x * PROJ_ROWS;
  int tid = threadIdx.x;
  for (int i = tid; i < PROJ_ROWS * 384; i += 1024)
    ((uint32_t*)arow)[i] = out16[(size_t)r0 * 384 + i];
  __syncthreads();
  int cq = tid & 255, rg = tid >> 8;
  float acc[8][4];
  #pragma unroll
  for (int i = 0; i < 8; i++)
    #pragma unroll
    for (int j = 0; j < 4; j++) acc[i][j] = 0.f;
  for (int kk = 0; kk < 384; ++kk) {
    uint32_t w0 = Wp[(size_t)kk * 1024 + cq];
    uint32_t w1 = Wp[(size_t)kk * 1024 + cq + 256];
    uint32_t w2 = Wp[(size_t)kk * 1024 + cq + 512];
    uint32_t w3 = Wp[(size_t)kk * 1024 + cq + 768];
    #pragma unroll
    for (int i = 0; i < 8; i++) {
      uint32_t a = arow[rg * 8 + i][kk];
      acc[i][0] = dot2(w0, a, acc[i][0]); acc[i][1] = dot2(w1, a, acc[i][1]);
      acc[i][2] = dot2(w2, a, acc[i][2]); acc[i][3] = dot2(w3, a, acc[i][3]);
    }
  }
  #pragma unroll
  for (int i = 0; i < 8; i++) {
    size_t row = (size_t)r0 + rg * 8 + i;
    #pragma unroll
    for (int j = 0; j < 4; j++) {
      int c = cq + j * 256;
      out[row * 1024 + c] = acc[i][j] + b_proj[c];
    }
  }
}

// ---------------- workspace layout (bytes) — identical footprint to R1 ------
static const size_t WS_WG    = 0;                                  // uint4[512*512] = 4 MiB
static const size_t WS_WHD   = WS_WG  + (size_t)512 * 512 * 16;    // uint4[256*128] = 512 KiB
static const size_t WS_WPJ   = WS_WHD + (size_t)256 * 128 * 16;    // uint[384*1024] = 1.5 MiB
static const size_t WS_OUT16 = WS_WPJ + (size_t)384 * 1024 * 4;    // uint[16384*384] = 24 MiB

extern "C" void kernel_launch(void* const* d_in, const int* in_sizes, int n_in,
                              void* d_out, int out_size, void* d_ws, size_t ws_size,
                              hipStream_t stream) {
  (void)in_sizes; (void)n_in; (void)out_size; (void)ws_size;
  const float* x       = (const float*)d_in[0];
  const float* W_ih    = (const float*)d_in[1];
  const float* W_hh    = (const float*)d_in[2];
  const float* b_ih    = (const float*)d_in[3];
  const float* b_hh    = (const float*)d_in[4];
  const float* ln_in_g = (const float*)d_in[5];
  const float* ln_in_b = (const float*)d_in[6];
  const float* ln_h_g  = (const float*)d_in[7];
  const float* ln_h_b  = (const float*)d_in[8];
  const float* W_rk    = (const float*)d_in[9];
  const float* b_rk    = (const float*)d_in[10];
  const float* W_wk    = (const float*)d_in[11];
  const float* b_wk    = (const float*)d_in[12];
  const float* W_ws    = (const float*)d_in[13];
  const float* b_ws    = (const float*)d_in[14];
  const float* W_er    = (const float*)d_in[15];
  const float* b_er    = (const float*)d_in[16];
  const float* W_ad    = (const float*)d_in[17];
  const float* b_ad    = (const float*)d_in[18];
  const float* ln_rk_g = (const float*)d_in[19];
  const float* ln_rk_b = (const float*)d_in[20];
  const float* ln_wk_g = (const float*)d_in[21];
  const float* ln_wk_b = (const float*)d_in[22];
  const float* ln_mem_g= (const float*)d_in[23];
  const float* ln_mem_b= (const float*)d_in[24];
  const float* ln_out_g= (const float*)d_in[25];
  const float* ln_out_b= (const float*)d_in[26];
  const float* W_proj  = (const float*)d_in[27];
  const float* b_proj  = (const float*)d_in[28];

  char* ws = (char*)d_ws;
  uint4*    Wg4   = (uint4*)(ws + WS_WG);
  uint4*    Whd4  = (uint4*)(ws + WS_WHD);
  uint32_t* Wp    = (uint32_t*)(ws + WS_WPJ);
  uint32_t* out16 = (uint32_t*)(ws + WS_OUT16);

  hipLaunchKernelGGL(pack_gates4, dim3(1024), dim3(256), 0, stream, W_ih, W_hh, Wg4);
  hipLaunchKernelGGL(pack_heads4, dim3(128), dim3(256), 0, stream,
                     W_rk, W_wk, W_ws, W_er, W_ad, Whd4);
  hipLaunchKernelGGL(pack_proj, dim3(1536), dim3(256), 0, stream, W_proj, Wp);

  Params p;
  p.x = x; p.b_ih = b_ih; p.b_hh = b_hh;
  p.ln_in_g = ln_in_g; p.ln_in_b = ln_in_b; p.ln_h_g = ln_h_g; p.ln_h_b = ln_h_b;
  p.b_rk = b_rk; p.b_wk = b_wk; p.b_ws = b_ws; p.b_er = b_er; p.b_ad = b_ad;
  p.ln_rk_g = ln_rk_g; p.ln_rk_b = ln_rk_b; p.ln_wk_g = ln_wk_g; p.ln_wk_b = ln_wk_b;
  p.ln_mem_g = ln_mem_g; p.ln_mem_b = ln_mem_b; p.ln_out_g = ln_out_g; p.ln_out_b = ln_out_b;
  p.Wg4 = Wg4; p.Whd4 = Whd4; p.out16 = out16; p.out = (float*)d_out;

  hipLaunchKernelGGL(dnc_recur, dim3(Bn), dim3(TB), SMEM_BYTES, stream, p);
  hipLaunchKernelGGL(proj_gemm, dim3((Bn * Ln) / PROJ_ROWS), dim3(1024), 0, stream,
                     out16, Wp, b_proj, (float*)d_out);
}